// Round 13
// baseline (301.899 us; speedup 1.0000x reference)
//
#include <hip/hip_runtime.h>

#define N_NODES 10000
#define D 128
#define N_EDGES 640000
#define NB 256                 // histogram blocks
#define HTHR 512               // hist threads
#define EPB (N_EDGES / NB)     // 2500 edges per block
#define SB 40                  // scan blocks (lookback)
#define NPSB 250               // nodes per scan block
#define NGRID 500              // K2 blocks (co-resident even at 2 blocks/CU)

typedef __attribute__((ext_vector_type(8))) short bf16x8;          // MFMA A/B frag
typedef __attribute__((ext_vector_type(4))) float f32x4;           // MFMA acc
typedef __attribute__((ext_vector_type(8))) unsigned short us8;    // 16B bf16 chunk
typedef __attribute__((ext_vector_type(8))) float f32x8;

__device__ __forceinline__ unsigned short f2bf(float f) {
    union { float f; unsigned int i; } v;
    v.f = f;
    unsigned int b = v.i;
    unsigned int rounded = b + 0x7fffu + ((b >> 16) & 1u);  // RNE
    return (unsigned short)(rounded >> 16);
}

__device__ __forceinline__ float bf2f(unsigned short u) {
    union { unsigned int i; float f; } v;
    v.i = ((unsigned int)u) << 16;
    return v.f;
}

__device__ __forceinline__ f32x8 bf2f8(us8 v) {
    f32x8 r;
#pragma unroll
    for (int t = 0; t < 8; ++t) r[t] = bf2f(v[t]);
    return r;
}

// grid barrier: counter zeroed by K1; target = epoch*NGRID.
__device__ __forceinline__ void gbar(unsigned int* bar, unsigned int target) {
    __syncthreads();
    if (threadIdx.x == 0) {
        __builtin_amdgcn_fence(__ATOMIC_RELEASE, "agent");
        __hip_atomic_fetch_add(bar, 1u, __ATOMIC_ACQ_REL, __HIP_MEMORY_SCOPE_AGENT);
        while (__hip_atomic_load(bar, __ATOMIC_ACQUIRE, __HIP_MEMORY_SCOPE_AGENT) < target)
            __builtin_amdgcn_s_sleep(2);
        __builtin_amdgcn_fence(__ATOMIC_ACQUIRE, "agent");
    }
    __syncthreads();
}

// ---------------- K1: cast x/W to bf16 + per-block LDS histogram ----------------

__global__ __launch_bounds__(HTHR) void hist_cast_kernel(const int* __restrict__ ei,
                                                         const float4* __restrict__ x4,
                                                         const float4* __restrict__ Wl4,
                                                         const float4* __restrict__ Wr4,
                                                         ushort4* __restrict__ xh4,
                                                         ushort4* __restrict__ Wlb4,
                                                         ushort4* __restrict__ Wrb4,
                                                         unsigned short* __restrict__ lrank,
                                                         unsigned short* __restrict__ cnt,
                                                         unsigned long long* __restrict__ flags) {
    __shared__ int h[N_NODES];
    const int tid = threadIdx.x;
    const int b = blockIdx.x;
    for (int n = tid; n < N_NODES; n += HTHR) h[n] = 0;
    if (b == 0 && tid < 64) flags[tid] = 0ULL;      // lookback flags + K2 barrier word

    const int gid = b * HTHR + tid;                 // 131072 threads
    for (int i = gid; i < N_NODES * D / 4; i += NB * HTHR) {
        float4 v = x4[i];
        ushort4 o;
        o.x = f2bf(v.x); o.y = f2bf(v.y); o.z = f2bf(v.z); o.w = f2bf(v.w);
        xh4[i] = o;
    }
    if (gid < D * D / 4) {
        float4 a = Wl4[gid], c = Wr4[gid];
        ushort4 oa, oc;
        oa.x = f2bf(a.x); oa.y = f2bf(a.y); oa.z = f2bf(a.z); oa.w = f2bf(a.w);
        oc.x = f2bf(c.x); oc.y = f2bf(c.y); oc.z = f2bf(c.z); oc.w = f2bf(c.w);
        Wlb4[gid] = oa;
        Wrb4[gid] = oc;
    }
    __syncthreads();

    const int base = b * EPB;
    for (int e = base + tid; e < base + EPB; e += HTHR) {
        int d = ei[N_EDGES + e];                    // row 1 = dst
        lrank[e] = (unsigned short)atomicAdd(&h[d], 1);
    }
    __syncthreads();
    unsigned short* c = cnt + (size_t)b * N_NODES;
    for (int n = tid; n < N_NODES; n += HTHR) c[n] = (unsigned short)h[n];
}

// ---------------- K2: colscan -> bar -> scatter -> bar -> aggregate+MFMA lin ----

__global__ __launch_bounds__(256, 3) void sage_tail_kernel(const float* __restrict__ x,
                                                           const int* __restrict__ ei,
                                                           const unsigned short* __restrict__ xh,
                                                           const unsigned short* __restrict__ Wlb,
                                                           const unsigned short* __restrict__ Wrb,
                                                           const float* __restrict__ bl,
                                                           unsigned short* __restrict__ cnt,
                                                           unsigned short* __restrict__ lrank,
                                                           unsigned short* __restrict__ csr,
                                                           int* __restrict__ row_start,
                                                           unsigned long long* __restrict__ flags,
                                                           float* __restrict__ out) {
    __shared__ int sc[258];
    __shared__ __align__(16) unsigned short atile[16][136];   // 272B row stride
    unsigned int* bar = (unsigned int*)(flags + 48);
    const int t = threadIdx.x;
    const int b = blockIdx.x;

    // ---- P2: column scan + node scan (first SB blocks; wave-parallel lookback) ----
    if (b < SB) {
        const int n = b * NPSB + t;
        int deg = 0;
        if (t < NPSB) {
            int s = 0;
#pragma unroll 16
            for (int j = 0; j < NB; ++j) {
                int idx = j * N_NODES + n;
                int v = cnt[idx];
                cnt[idx] = (unsigned short)s;      // exclusive prefix within column
                s += v;
            }
            deg = s;
        }
        sc[t] = deg;
        __syncthreads();
        for (int off = 1; off < 256; off <<= 1) {
            int v = (t >= off) ? sc[t - off] : 0;
            __syncthreads();
            sc[t] += v;
            __syncthreads();
        }
        const int total = sc[255];
        const int local_excl = sc[t] - deg;
        __syncthreads();

        if (b == 0) {
            if (t == 0) {
                __hip_atomic_store(&flags[0], (2ULL << 32) | (unsigned)total,
                                   __ATOMIC_RELEASE, __HIP_MEMORY_SCOPE_AGENT);
                sc[256] = 0;
            }
        } else {
            if (t == 0) {
                __hip_atomic_store(&flags[b], (1ULL << 32) | (unsigned)total,
                                   __ATOMIC_RELEASE, __HIP_MEMORY_SCOPE_AGENT);
            }
            if (t < 64) {                          // wave 0: parallel lookback
                const unsigned long long mask_b = (1ULL << b) - 1;
                int excl;
                for (;;) {
                    unsigned long long f = (t < b)
                        ? __hip_atomic_load(&flags[t], __ATOMIC_ACQUIRE, __HIP_MEMORY_SCOPE_AGENT)
                        : (2ULL << 32);
                    unsigned st = (unsigned)(f >> 32);
                    unsigned long long ready = __ballot(st >= 1);
                    if ((ready & mask_b) == mask_b) {
                        unsigned long long b2 = __ballot(st == 2) & mask_b;
                        int j = 63 - __builtin_clzll(b2 | 1ULL);
                        int v = (t >= j && t < b) ? (int)(unsigned)(f & 0xffffffffULL) : 0;
#pragma unroll
                        for (int off = 32; off > 0; off >>= 1) v += __shfl_down(v, off, 64);
                        excl = __shfl(v, 0, 64);
                        break;
                    }
                }
                if (t == 0) {
                    __hip_atomic_store(&flags[b], (2ULL << 32) | (unsigned)(excl + total),
                                       __ATOMIC_RELEASE, __HIP_MEMORY_SCOPE_AGENT);
                    sc[256] = excl;
                }
            }
        }
        __syncthreads();
        if (t < NPSB) row_start[n] = sc[256] + local_excl;
        if (b == SB - 1 && t == 0) row_start[N_NODES] = N_EDGES;
    }

    gbar(bar, 1 * NGRID);

    // ---- P3: atomic-free scatter (grid-stride) ----
    for (int i = b * 256 + t; i < N_EDGES; i += NGRID * 256) {
        int eb = i / EPB;
        int s = ei[i];
        int d = ei[N_EDGES + i];
        int pos = row_start[d] + (int)cnt[(size_t)eb * N_NODES + d] + (int)lrank[i];
        csr[pos] = (unsigned short)s;
    }

    gbar(bar, 2 * NGRID);

    // ---- P4+P5: aggregate 16-node tile into LDS, MFMA lin ----
    const int wave = t >> 6;
    const int lane = t & 63;
    const int slot = lane >> 4;        // 0..3
    const int lane16 = lane & 15;      // feature octet
    const int l15 = lane & 15;
    const int quad = lane >> 4;
    const us8* xh8 = (const us8*)xh;

    for (int tile = b; tile < 625; tile += NGRID) {
        const int row0 = tile * 16;

#pragma unroll
        for (int q = 0; q < 4; ++q) {
            const int node = row0 + wave * 4 + q;
            const int start = row_start[node];
            const int end = row_start[node + 1];
            f32x8 a0 = 0.f, a1 = 0.f, a2 = 0.f, a3 = 0.f;
            int j = start + slot;
            for (; j + 12 < end; j += 16) {
                int i0 = csr[j], i1 = csr[j + 4], i2 = csr[j + 8], i3 = csr[j + 12];
                us8 v0 = xh8[i0 * 16 + lane16];
                us8 v1 = xh8[i1 * 16 + lane16];
                us8 v2 = xh8[i2 * 16 + lane16];
                us8 v3 = xh8[i3 * 16 + lane16];
                a0 += bf2f8(v0); a1 += bf2f8(v1); a2 += bf2f8(v2); a3 += bf2f8(v3);
            }
            for (; j < end; j += 4) a0 += bf2f8(xh8[(int)csr[j] * 16 + lane16]);
            a0 = (a0 + a1) + (a2 + a3);
#pragma unroll
            for (int c = 0; c < 8; ++c) {
                float v = a0[c];
                v += __shfl_xor(v, 16, 64);
                v += __shfl_xor(v, 32, 64);
                a0[c] = v;
            }
            if (slot == 0) {
                int cntE = end - start;
                float inv = (cntE > 0) ? 1.0f / (float)cntE : 0.0f;
                us8 pack;
#pragma unroll
                for (int u = 0; u < 8; ++u) pack[u] = f2bf(a0[u] * inv);
                *(us8*)&atile[wave * 4 + q][lane16 * 8] = pack;
            }
        }
        __syncthreads();

        const int m = row0 + l15;
        const bf16x8* xrow = (const bf16x8*)(xh + (size_t)m * D) + quad;

        for (int ft = wave; ft < 8; ft += 4) {
            const int out0 = ft * 16;
            const int f = out0 + l15;
            const bf16x8* wlro = (const bf16x8*)(Wlb + (size_t)f * D) + quad;
            const bf16x8* wrro = (const bf16x8*)(Wrb + (size_t)f * D) + quad;

            f32x4 c = {0.f, 0.f, 0.f, 0.f};
#pragma unroll
            for (int kk = 0; kk < 4; ++kk) {
                bf16x8 afrag = *(const bf16x8*)&atile[l15][quad * 8 + kk * 32];
                c = __builtin_amdgcn_mfma_f32_16x16x32_bf16(afrag, wlro[kk * 4], c, 0, 0, 0);
                c = __builtin_amdgcn_mfma_f32_16x16x32_bf16(xrow[kk * 4], wrro[kk * 4], c, 0, 0, 0);
            }

            const float bias = bl[f];
#pragma unroll
            for (int r = 0; r < 4; ++r) {
                int row = row0 + quad * 4 + r;
                int idx = row * D + f;
                out[idx] = x[idx] + bias + c[r];
            }
        }
        __syncthreads();   // protect atile before next tile overwrites
    }
}

extern "C" void kernel_launch(void* const* d_in, const int* in_sizes, int n_in,
                              void* d_out, int out_size, void* d_ws, size_t ws_size,
                              hipStream_t stream) {
    const float* x  = (const float*)d_in[0];
    const int*   ei = (const int*)d_in[1];     // [2, E] int32
    const float* Wl = (const float*)d_in[2];
    const float* bl = (const float*)d_in[3];
    const float* Wr = (const float*)d_in[4];
    float* out = (float*)d_out;

    // workspace layout (16B-aligned segments)
    unsigned long long* flags = (unsigned long long*)d_ws;               // 64 ULL
    int* row_start = (int*)(flags + 64);                                 // 10016 ints
    unsigned short* cnt   = (unsigned short*)(row_start + 10016);        // NB*N_NODES us
    unsigned short* lrank = cnt + (size_t)NB * N_NODES;                  // N_EDGES us
    unsigned short* csr   = lrank + N_EDGES;                             // N_EDGES us
    unsigned short* xh    = csr + N_EDGES;                               // N_NODES*D bf16
    unsigned short* Wlb   = xh + (size_t)N_NODES * D;                    // D*D bf16
    unsigned short* Wrb   = Wlb + D * D;                                 // D*D bf16

    hist_cast_kernel<<<NB, HTHR, 0, stream>>>(ei, (const float4*)x, (const float4*)Wl,
                                              (const float4*)Wr, (ushort4*)xh,
                                              (ushort4*)Wlb, (ushort4*)Wrb,
                                              lrank, cnt, flags);
    sage_tail_kernel<<<NGRID, 256, 0, stream>>>(x, ei, xh, Wlb, Wrb, bl,
                                                cnt, lrank, csr, row_start, flags, out);
}

// Round 14
// 136.966 us; speedup vs baseline: 2.2042x; 2.2042x over previous
//
#include <hip/hip_runtime.h>

#define N_NODES 10000
#define D 128
#define N_EDGES 640000
#define NB 256                 // histogram blocks
#define HTHR 512               // hist threads
#define EPB (N_EDGES / NB)     // 2500 edges per block
#define SB 64                  // scan blocks (lookback, <=64 for ballot mask)
#define NPSB 157               // nodes per scan block (64*157 = 10048 >= 10001)

typedef __attribute__((ext_vector_type(8))) short bf16x8;          // MFMA A/B frag
typedef __attribute__((ext_vector_type(4))) float f32x4;           // MFMA acc
typedef __attribute__((ext_vector_type(8))) unsigned short us8;    // 16B bf16 chunk
typedef __attribute__((ext_vector_type(8))) float f32x8;

__device__ __forceinline__ unsigned short f2bf(float f) {
    union { float f; unsigned int i; } v;
    v.f = f;
    unsigned int b = v.i;
    unsigned int rounded = b + 0x7fffu + ((b >> 16) & 1u);  // RNE
    return (unsigned short)(rounded >> 16);
}

__device__ __forceinline__ float bf2f(unsigned short u) {
    union { unsigned int i; float f; } v;
    v.i = ((unsigned int)u) << 16;
    return v.f;
}

__device__ __forceinline__ f32x8 bf2f8(us8 v) {
    f32x8 r;
#pragma unroll
    for (int t = 0; t < 8; ++t) r[t] = bf2f(v[t]);
    return r;
}

// ---------------- K1: cast x/W to bf16 + per-block LDS histogram ----------------

__global__ __launch_bounds__(HTHR) void hist_cast_kernel(const int* __restrict__ ei,
                                                         const float4* __restrict__ x4,
                                                         const float4* __restrict__ Wl4,
                                                         const float4* __restrict__ Wr4,
                                                         ushort4* __restrict__ xh4,
                                                         ushort4* __restrict__ Wlb4,
                                                         ushort4* __restrict__ Wrb4,
                                                         unsigned short* __restrict__ lrank,
                                                         unsigned short* __restrict__ cnt,
                                                         unsigned long long* __restrict__ flags) {
    __shared__ int h[N_NODES];
    const int tid = threadIdx.x;
    const int b = blockIdx.x;
    for (int n = tid; n < N_NODES; n += HTHR) h[n] = 0;
    if (b == 0 && tid < SB) flags[tid] = 0ULL;

    const int gid = b * HTHR + tid;                 // 131072 threads
    for (int i = gid; i < N_NODES * D / 4; i += NB * HTHR) {
        float4 v = x4[i];
        ushort4 o;
        o.x = f2bf(v.x); o.y = f2bf(v.y); o.z = f2bf(v.z); o.w = f2bf(v.w);
        xh4[i] = o;
    }
    if (gid < D * D / 4) {
        float4 a = Wl4[gid], c = Wr4[gid];
        ushort4 oa, oc;
        oa.x = f2bf(a.x); oa.y = f2bf(a.y); oa.z = f2bf(a.z); oa.w = f2bf(a.w);
        oc.x = f2bf(c.x); oc.y = f2bf(c.y); oc.z = f2bf(c.z); oc.w = f2bf(c.w);
        Wlb4[gid] = oa;
        Wrb4[gid] = oc;
    }
    __syncthreads();

    const int base = b * EPB;
    for (int e = base + tid; e < base + EPB; e += HTHR) {
        int d = ei[N_EDGES + e];                    // row 1 = dst
        lrank[e] = (unsigned short)atomicAdd(&h[d], 1);
    }
    __syncthreads();
    unsigned short* c = cnt + (size_t)b * N_NODES;
    for (int n = tid; n < N_NODES; n += HTHR) c[n] = (unsigned short)h[n];
}

// ---------------- K2: column scan + node scan (wave-parallel lookback) ----------

__global__ __launch_bounds__(256) void colscan_scan_kernel(unsigned short* __restrict__ cnt,
                                                           int* __restrict__ row_start,
                                                           unsigned long long* __restrict__ flags) {
    const int t = threadIdx.x;
    const int b = blockIdx.x;
    const int n = b * NPSB + t;            // valid for t < NPSB && n < N_NODES
    const bool live = (t < NPSB) && (n < N_NODES);
    __shared__ int sc[258];

    int deg = 0;
    if (live) {
        int s = 0;
#pragma unroll 16
        for (int j = 0; j < NB; ++j) {
            int idx = j * N_NODES + n;
            int v = cnt[idx];
            cnt[idx] = (unsigned short)s;  // exclusive prefix within column
            s += v;
        }
        deg = s;
    }
    sc[t] = deg;
    __syncthreads();
    for (int off = 1; off < 256; off <<= 1) {
        int v = (t >= off) ? sc[t - off] : 0;
        __syncthreads();
        sc[t] += v;
        __syncthreads();
    }
    const int total = sc[255];
    const int local_excl = sc[t] - deg;
    __syncthreads();

    if (b == 0) {
        if (t == 0) {
            __hip_atomic_store(&flags[0], (2ULL << 32) | (unsigned)total,
                               __ATOMIC_RELEASE, __HIP_MEMORY_SCOPE_AGENT);
            sc[256] = 0;
        }
    } else {
        if (t == 0) {
            __hip_atomic_store(&flags[b], (1ULL << 32) | (unsigned)total,
                               __ATOMIC_RELEASE, __HIP_MEMORY_SCOPE_AGENT);
        }
        if (t < 64) {                      // wave 0: parallel lookback
            const unsigned long long mask_b = (b >= 64) ? ~0ULL : ((1ULL << b) - 1);
            int excl;
            for (;;) {
                unsigned long long f = (t < b)
                    ? __hip_atomic_load(&flags[t], __ATOMIC_ACQUIRE, __HIP_MEMORY_SCOPE_AGENT)
                    : (2ULL << 32);
                unsigned st = (unsigned)(f >> 32);
                unsigned long long ready = __ballot(st >= 1);
                if ((ready & mask_b) == mask_b) {
                    unsigned long long b2 = __ballot(st == 2) & mask_b;
                    int j = 63 - __builtin_clzll(b2 | 1ULL);
                    int v = (t >= j && t < b) ? (int)(unsigned)(f & 0xffffffffULL) : 0;
#pragma unroll
                    for (int off = 32; off > 0; off >>= 1) v += __shfl_down(v, off, 64);
                    excl = __shfl(v, 0, 64);
                    break;
                }
            }
            if (t == 0) {
                __hip_atomic_store(&flags[b], (2ULL << 32) | (unsigned)(excl + total),
                                   __ATOMIC_RELEASE, __HIP_MEMORY_SCOPE_AGENT);
                sc[256] = excl;
            }
        }
    }
    __syncthreads();
    if (live) row_start[n] = sc[256] + local_excl;
    if (b == SB - 1 && t == 0) row_start[N_NODES] = N_EDGES;
}

// ---------------- K3: atomic-free scatter (NT stores) ----------------

__global__ __launch_bounds__(256) void scatter_kernel(const int* __restrict__ ei,
                                                      const int* __restrict__ row_start,
                                                      const unsigned short* __restrict__ cnt,
                                                      const unsigned short* __restrict__ lrank,
                                                      unsigned short* __restrict__ csr) {
    int i = blockIdx.x * 256 + threadIdx.x;
    if (i < N_EDGES) {
        int b = i / EPB;
        int s = ei[i];
        int d = ei[N_EDGES + i];
        int pos = row_start[d] + (int)cnt[(size_t)b * N_NODES + d] + (int)lrank[i];
        __builtin_nontemporal_store((unsigned short)s, &csr[pos]);
    }
}

// ---------------- K4: aggregate 16-node tile in LDS, MFMA lin ----------------

__global__ __launch_bounds__(256) void agg_lin_kernel(const float* __restrict__ x,
                                                      const unsigned short* __restrict__ xh,
                                                      const int* __restrict__ row_start,
                                                      const unsigned short* __restrict__ csr,
                                                      const unsigned short* __restrict__ Wlb,
                                                      const unsigned short* __restrict__ Wrb,
                                                      const float* __restrict__ bl,
                                                      float* __restrict__ out) {
    __shared__ __align__(16) unsigned short atile[16][136];   // 272B row stride
    const int tid = threadIdx.x;
    const int wave = tid >> 6;
    const int lane = tid & 63;
    const int slot = lane >> 4;        // 0..3
    const int lane16 = lane & 15;      // feature octet
    const int row0 = blockIdx.x * 16;
    const us8* xh8 = (const us8*)xh;

    // ---- aggregation: 4 nodes per wave ----
#pragma unroll
    for (int q = 0; q < 4; ++q) {
        const int node = row0 + wave * 4 + q;
        const int start = row_start[node];
        const int end = row_start[node + 1];
        f32x8 a0 = 0.f, a1 = 0.f, a2 = 0.f, a3 = 0.f;
        int j = start + slot;
        for (; j + 12 < end; j += 16) {
            int i0 = csr[j], i1 = csr[j + 4], i2 = csr[j + 8], i3 = csr[j + 12];
            us8 v0 = xh8[i0 * 16 + lane16];
            us8 v1 = xh8[i1 * 16 + lane16];
            us8 v2 = xh8[i2 * 16 + lane16];
            us8 v3 = xh8[i3 * 16 + lane16];
            a0 += bf2f8(v0); a1 += bf2f8(v1); a2 += bf2f8(v2); a3 += bf2f8(v3);
        }
        for (; j < end; j += 4) a0 += bf2f8(xh8[(int)csr[j] * 16 + lane16]);
        a0 = (a0 + a1) + (a2 + a3);
#pragma unroll
        for (int c = 0; c < 8; ++c) {
            float v = a0[c];
            v += __shfl_xor(v, 16, 64);
            v += __shfl_xor(v, 32, 64);
            a0[c] = v;
        }
        if (slot == 0) {
            int cntE = end - start;
            float inv = (cntE > 0) ? 1.0f / (float)cntE : 0.0f;
            us8 pack;
#pragma unroll
            for (int u = 0; u < 8; ++u) pack[u] = f2bf(a0[u] * inv);
            *(us8*)&atile[wave * 4 + q][lane16 * 8] = pack;
        }
    }
    __syncthreads();

    // ---- MFMA lin: 8 F-tiles over 4 waves ----
    const int l15 = lane & 15;
    const int quad = lane >> 4;
    const int m = row0 + l15;
    const bf16x8* xrow = (const bf16x8*)(xh + (size_t)m * D) + quad;

    for (int ft = wave; ft < 8; ft += 4) {
        const int out0 = ft * 16;
        const int f = out0 + l15;
        const bf16x8* wlro = (const bf16x8*)(Wlb + (size_t)f * D) + quad;
        const bf16x8* wrro = (const bf16x8*)(Wrb + (size_t)f * D) + quad;

        f32x4 c = {0.f, 0.f, 0.f, 0.f};
#pragma unroll
        for (int kk = 0; kk < 4; ++kk) {
            bf16x8 afrag = *(const bf16x8*)&atile[l15][quad * 8 + kk * 32];
            c = __builtin_amdgcn_mfma_f32_16x16x32_bf16(afrag, wlro[kk * 4], c, 0, 0, 0);
            c = __builtin_amdgcn_mfma_f32_16x16x32_bf16(xrow[kk * 4], wrro[kk * 4], c, 0, 0, 0);
        }

        const float bias = bl[f];
#pragma unroll
        for (int r = 0; r < 4; ++r) {
            int row = row0 + quad * 4 + r;
            int idx = row * D + f;
            out[idx] = x[idx] + bias + c[r];
        }
    }
}

extern "C" void kernel_launch(void* const* d_in, const int* in_sizes, int n_in,
                              void* d_out, int out_size, void* d_ws, size_t ws_size,
                              hipStream_t stream) {
    const float* x  = (const float*)d_in[0];
    const int*   ei = (const int*)d_in[1];     // [2, E] int32
    const float* Wl = (const float*)d_in[2];
    const float* bl = (const float*)d_in[3];
    const float* Wr = (const float*)d_in[4];
    float* out = (float*)d_out;

    // workspace layout (16B-aligned segments)
    unsigned long long* flags = (unsigned long long*)d_ws;               // 64 ULL
    int* row_start = (int*)(flags + 64);                                 // 10016 ints
    unsigned short* cnt   = (unsigned short*)(row_start + 10016);        // NB*N_NODES us
    unsigned short* lrank = cnt + (size_t)NB * N_NODES;                  // N_EDGES us
    unsigned short* csr   = lrank + N_EDGES;                             // N_EDGES us
    unsigned short* xh    = csr + N_EDGES;                               // N_NODES*D bf16
    unsigned short* Wlb   = xh + (size_t)N_NODES * D;                    // D*D bf16
    unsigned short* Wrb   = Wlb + D * D;                                 // D*D bf16

    hist_cast_kernel<<<NB, HTHR, 0, stream>>>(ei, (const float4*)x, (const float4*)Wl,
                                              (const float4*)Wr, (ushort4*)xh,
                                              (ushort4*)Wlb, (ushort4*)Wrb,
                                              lrank, cnt, flags);
    colscan_scan_kernel<<<SB, 256, 0, stream>>>(cnt, row_start, flags);
    scatter_kernel<<<(N_EDGES + 255) / 256, 256, 0, stream>>>(ei, row_start, cnt, lrank, csr);
    agg_lin_kernel<<<N_NODES / 16, 256, 0, stream>>>(x, xh, row_start, csr,
                                                     Wlb, Wrb, bl, out);
}